// Round 9
// baseline (284.182 us; speedup 1.0000x reference)
//
#include <hip/hip_runtime.h>

#define NEG 0.2f

typedef __attribute__((ext_vector_type(8))) short short8;
typedef __attribute__((ext_vector_type(4))) float f32x4;

__device__ __forceinline__ float lrelu(float v) { return v > 0.f ? v : NEG * v; }

__device__ __forceinline__ unsigned short f2bf(float f) {
    unsigned u = __float_as_uint(f);
    unsigned r = (u + 0x7FFF + ((u >> 16) & 1)) >> 16;   // RNE
    return (unsigned short)r;
}
__device__ __forceinline__ float bf2f(unsigned short h) { return __uint_as_float((unsigned)h << 16); }
__device__ __forceinline__ float bf_lo(unsigned v) { return __uint_as_float(v << 16); }
__device__ __forceinline__ float bf_hi(unsigned v) { return __uint_as_float(v & 0xffff0000u); }

// Fused weight prep.
// Wt1_{hi,lo}[80][128] bf16 T: cols 0..63 = W1; 64+j = W1[:,h*32:+32]@att (j:0=src_h0,1=src_h1,2=dst_h0,3=dst_h1); 68..79=0
// Wt2_{hi,lo}[48][64]  bf16 T: cols 0..15 = W_mu, 16..31 = W_ls, 32..35 = att proj (src_mu,dst_mu,src_ls,dst_ls), 36..47 = 0
__global__ void build_w(const float* __restrict__ W1, const float* __restrict__ as1,
                        const float* __restrict__ ad1,
                        const float* __restrict__ Wmu, const float* __restrict__ Wls,
                        const float* __restrict__ asmu, const float* __restrict__ admu,
                        const float* __restrict__ asls, const float* __restrict__ adls,
                        unsigned short* __restrict__ w1h, unsigned short* __restrict__ w1l,
                        unsigned short* __restrict__ w2h, unsigned short* __restrict__ w2l) {
    int i = blockIdx.x * blockDim.x + threadIdx.x;
    if (i < 128 * 80) {
        int k = i / 80, c = i % 80;
        float val;
        if (c < 64) val = W1[k * 64 + c];
        else if (c < 68) {
            int j = c - 64;
            int hh = j & 1;
            const float* att = (j >= 2) ? ad1 : as1;
            float s = 0.f;
            for (int d = 0; d < 32; ++d) s += W1[k * 64 + hh * 32 + d] * att[hh * 32 + d];
            val = s;
        } else val = 0.f;
        unsigned short h = f2bf(val);
        w1h[c * 128 + k] = h;
        w1l[c * 128 + k] = f2bf(val - bf2f(h));
    } else {
        int i2 = i - 128 * 80;
        if (i2 >= 64 * 48) return;
        int k = i2 / 48, c = i2 % 48;
        float val;
        if (c < 16) val = Wmu[k * 16 + c];
        else if (c < 32) val = Wls[k * 16 + (c - 16)];
        else if (c < 36) {
            int j = c - 32;
            const float* W = (j < 2) ? Wmu : Wls;
            const float* att = (j == 0) ? asmu : (j == 1) ? admu : (j == 2) ? asls : adls;
            float s = 0.f;
            for (int c2 = 0; c2 < 16; ++c2) s += W[k * 16 + c2] * att[c2];
            val = s;
        } else val = 0.f;
        unsigned short h = f2bf(val);
        w2h[c * 64 + k] = h;
        w2l[c * 64 + k] = f2bf(val - bf2f(h));
    }
}

// MFMA gemm1: hbf[N][64] bf16 = x @ W1, a1[N][4] f32, a1s[N] float2 (src_h0,src_h1). No LDS.
__global__ __launch_bounds__(256) void gemm1(const float* __restrict__ x,
                                             const unsigned short* __restrict__ Wt_hi,
                                             const unsigned short* __restrict__ Wt_lo,
                                             unsigned short* __restrict__ hbf,
                                             float* __restrict__ a1, float2* __restrict__ a1s, int n) {
    int wid = threadIdx.x >> 6, lane = threadIdx.x & 63;
    int m = lane & 15, b = lane >> 4;
    int row = blockIdx.x * 64 + wid * 16 + m;
    int rowc = min(row, n - 1);
    short8 ah[4], al[4];
    const float* xp = x + (size_t)rowc * 128 + b * 8;
#pragma unroll
    for (int kc = 0; kc < 4; ++kc) {
        float4 v0 = *(const float4*)(xp + kc * 32);
        float4 v1 = *(const float4*)(xp + kc * 32 + 4);
        float vv[8] = {v0.x, v0.y, v0.z, v0.w, v1.x, v1.y, v1.z, v1.w};
#pragma unroll
        for (int j = 0; j < 8; ++j) {
            unsigned short h = f2bf(vv[j]);
            ah[kc][j] = (short)h;
            al[kc][j] = (short)f2bf(vv[j] - bf2f(h));
        }
    }
    int orow0 = blockIdx.x * 64 + wid * 16 + b * 4;
#pragma unroll
    for (int ct = 0; ct < 5; ++ct) {
        f32x4 acc = {0.f, 0.f, 0.f, 0.f};
        int col = ct * 16 + m;
        const unsigned short* wh = Wt_hi + col * 128 + b * 8;
        const unsigned short* wl = Wt_lo + col * 128 + b * 8;
#pragma unroll
        for (int kc = 0; kc < 4; ++kc) {
            short8 bh = *(const short8*)(wh + kc * 32);
            short8 bl = *(const short8*)(wl + kc * 32);
            acc = __builtin_amdgcn_mfma_f32_16x16x32_bf16(ah[kc], bh, acc, 0, 0, 0);
            acc = __builtin_amdgcn_mfma_f32_16x16x32_bf16(al[kc], bh, acc, 0, 0, 0);
            acc = __builtin_amdgcn_mfma_f32_16x16x32_bf16(ah[kc], bl, acc, 0, 0, 0);
        }
        if (ct < 4) {
#pragma unroll
            for (int j = 0; j < 4; ++j) {
                int orow = orow0 + j;
                if (orow < n) hbf[(size_t)orow * 64 + ct * 16 + m] = f2bf(acc[j]);
            }
        } else {
            int base = lane & 48;
#pragma unroll
            for (int j = 0; j < 4; ++j) {
                float c0 = __shfl(acc[j], base + 0, 64);
                float c1 = __shfl(acc[j], base + 1, 64);
                int orow = orow0 + j;
                if (orow < n) {
                    if (m < 4) a1[(size_t)orow * 4 + m] = acc[j];
                    if (m == 0) a1s[orow] = make_float2(c0, c1);
                }
            }
        }
    }
}

// MFMA gemm2: hml[N][16] u32 (lo=mu,hi=ls), a2[N][4] f32, a2s[N] float2 (src_mu,src_ls).
__global__ __launch_bounds__(256) void gemm2(const unsigned short* __restrict__ h1bf,
                                             const unsigned short* __restrict__ Wt_hi,
                                             const unsigned short* __restrict__ Wt_lo,
                                             unsigned* __restrict__ hml, float* __restrict__ a2,
                                             float2* __restrict__ a2s, int n) {
    int wid = threadIdx.x >> 6, lane = threadIdx.x & 63;
    int m = lane & 15, b = lane >> 4;
    int row = blockIdx.x * 64 + wid * 16 + m;
    int rowc = min(row, n - 1);
    short8 a0 = *(const short8*)(h1bf + (size_t)rowc * 64 + b * 8);
    short8 a1f = *(const short8*)(h1bf + (size_t)rowc * 64 + 32 + b * 8);
    int orow0 = blockIdx.x * 64 + wid * 16 + b * 4;
    f32x4 accs[3];
#pragma unroll
    for (int ct = 0; ct < 3; ++ct) {
        f32x4 acc = {0.f, 0.f, 0.f, 0.f};
        int col = ct * 16 + m;
        const unsigned short* wh = Wt_hi + col * 64 + b * 8;
        const unsigned short* wl = Wt_lo + col * 64 + b * 8;
        short8 bh0 = *(const short8*)(wh);
        short8 bl0 = *(const short8*)(wl);
        short8 bh1 = *(const short8*)(wh + 32);
        short8 bl1 = *(const short8*)(wl + 32);
        acc = __builtin_amdgcn_mfma_f32_16x16x32_bf16(a0, bh0, acc, 0, 0, 0);
        acc = __builtin_amdgcn_mfma_f32_16x16x32_bf16(a0, bl0, acc, 0, 0, 0);
        acc = __builtin_amdgcn_mfma_f32_16x16x32_bf16(a1f, bh1, acc, 0, 0, 0);
        acc = __builtin_amdgcn_mfma_f32_16x16x32_bf16(a1f, bl1, acc, 0, 0, 0);
        accs[ct] = acc;
    }
    int base = lane & 48;
#pragma unroll
    for (int j = 0; j < 4; ++j) {
        int orow = orow0 + j;
        float c0 = __shfl(accs[2][j], base + 0, 64);
        float c2 = __shfl(accs[2][j], base + 2, 64);
        if (orow >= n) continue;
        hml[(size_t)orow * 16 + m] = ((unsigned)f2bf(accs[1][j]) << 16) | f2bf(accs[0][j]);
        if (m < 4) a2[(size_t)orow * 4 + m] = accs[2][j];
        if (m == 0) a2s[orow] = make_float2(c0, c2);
    }
}

// ---- XCD-partitioned CSR build ----
__global__ __launch_bounds__(256) void count_deg_part(const int* __restrict__ dstv, int E, int np,
                                                      int* __restrict__ deg) {
    int p = blockIdx.x & 7;
    int bslot = blockIdx.x >> 3;
    int nblk = gridDim.x >> 3;
    int lo = p * np, hi = lo + np;
    for (int i = bslot * 256 + threadIdx.x; i < E; i += nblk * 256) {
        int d = dstv[i];
        if (d >= lo && d < hi) atomicAdd(&deg[d], 1);
    }
}

__global__ __launch_bounds__(256) void scatter_part(const int* __restrict__ srcv,
                                                    const int* __restrict__ dstv, int E, int np,
                                                    int* __restrict__ cursor, int* __restrict__ srcs) {
    int p = blockIdx.x & 7;
    int bslot = blockIdx.x >> 3;
    int nblk = gridDim.x >> 3;
    int lo = p * np, hi = lo + np;
    for (int i = bslot * 256 + threadIdx.x; i < E; i += nblk * 256) {
        int d = dstv[i];
        if (d >= lo && d < hi) {
            int slot = atomicAdd(&cursor[d], 1);
            srcs[slot] = srcv[i];
        }
    }
}

__global__ __launch_bounds__(256) void block_sums(const int* __restrict__ deg, int n,
                                                  int* __restrict__ bsums) {
    int i = blockIdx.x * 256 + threadIdx.x;
    int v = (i < n) ? deg[i] : 0;
    for (int o = 32; o > 0; o >>= 1) v += __shfl_down(v, o, 64);
    __shared__ int ws[4];
    if ((threadIdx.x & 63) == 0) ws[threadIdx.x >> 6] = v;
    __syncthreads();
    if (threadIdx.x == 0) bsums[blockIdx.x] = ws[0] + ws[1] + ws[2] + ws[3];
}

// per-block: scan bsums in LDS for base, then local exclusive scan -> offs, cursor
__global__ __launch_bounds__(256) void write_offs(const int* __restrict__ deg,
                                                  const int* __restrict__ bsums, int nb, int n,
                                                  int* __restrict__ offs, int* __restrict__ cursor) {
    __shared__ int sb[256];
    __shared__ int s[256];
    int t = threadIdx.x;
    int bv = (t < nb) ? bsums[t] : 0;
    sb[t] = bv;
    __syncthreads();
    for (int o = 1; o < 256; o <<= 1) {
        int u = (t >= o) ? sb[t - o] : 0;
        __syncthreads();
        sb[t] += u;
        __syncthreads();
    }
    int base0 = (blockIdx.x == 0) ? 0 : sb[blockIdx.x - 1];
    int i = blockIdx.x * 256 + t;
    int v = (i < n) ? deg[i] : 0;
    s[t] = v;
    __syncthreads();
    for (int o = 1; o < 256; o <<= 1) {
        int u = (t >= o) ? s[t - o] : 0;
        __syncthreads();
        s[t] += u;
        __syncthreads();
    }
    int excl = s[t] - v + base0;
    if (i < n) { offs[i] = excl; cursor[i] = excl; }
    if (i == n - 1) offs[n] = excl + v;
}

// layer-1 aggregation: one wave per node; 4 edge phases; lane owns 4 ch.
// Wave-UNIFORM loop: all 64 lanes iterate together so __shfl sources are always active;
// per-lane tail handled by clamped index + zero weight.
__global__ __launch_bounds__(256) void agg1(const unsigned* __restrict__ h32, const float* __restrict__ a1,
                                            const float2* __restrict__ a1s,
                                            const int* __restrict__ offs, const int* __restrict__ srcs,
                                            const float* __restrict__ b1, unsigned* __restrict__ h1u, int n) {
    int wid = threadIdx.x >> 6, lane = threadIdx.x & 63;
    int node = blockIdx.x * 4 + wid;
    if (node >= n) return;
    int q = lane >> 4;
    int l = lane & 15;
    int head = l >> 3;
    float adst = a1[node * 4 + 2 + head];
    float ax = 0.f, ay = 0.f, az = 0.f, aw = 0.f, denom = 0.f;
    if (q == 0) {               // self loop
        float w = __expf(lrelu(a1[node * 4 + head] + adst));
        uint2 hv = *(const uint2*)&h32[node * 32 + 2 * l];
        ax = w * bf_lo(hv.x); ay = w * bf_hi(hv.x);
        az = w * bf_lo(hv.y); aw = w * bf_hi(hv.y);
        denom = w;
    }
    int kb = offs[node];
    int deg = offs[node + 1] - kb;
    int pre = (lane < deg) ? srcs[kb + lane] : 0;
    for (int idx0 = 0; idx0 < deg; idx0 += 4) {
        int idx = idx0 + q;
        int idc = min(idx, deg - 1);
        int s = (idc < 64) ? __shfl(pre, idc, 64) : srcs[kb + idc];
        float2 ap = a1s[s];
        float asrc = head ? ap.y : ap.x;
        float wv = (idx < deg) ? __expf(lrelu(asrc + adst)) : 0.f;
        uint2 hv = *(const uint2*)&h32[s * 32 + 2 * l];
        denom += wv;
        ax += wv * bf_lo(hv.x); ay += wv * bf_hi(hv.x);
        az += wv * bf_lo(hv.y); aw += wv * bf_hi(hv.y);
    }
    ax += __shfl_xor(ax, 16, 64); ax += __shfl_xor(ax, 32, 64);
    ay += __shfl_xor(ay, 16, 64); ay += __shfl_xor(ay, 32, 64);
    az += __shfl_xor(az, 16, 64); az += __shfl_xor(az, 32, 64);
    aw += __shfl_xor(aw, 16, 64); aw += __shfl_xor(aw, 32, 64);
    denom += __shfl_xor(denom, 16, 64); denom += __shfl_xor(denom, 32, 64);
    if (q == 0) {
        float4 bv = *(const float4*)&b1[4 * l];
        float o0 = fmaxf(ax / denom + bv.x, 0.f);
        float o1 = fmaxf(ay / denom + bv.y, 0.f);
        float o2 = fmaxf(az / denom + bv.z, 0.f);
        float o3 = fmaxf(aw / denom + bv.w, 0.f);
        uint2 o;
        o.x = ((unsigned)f2bf(o1) << 16) | f2bf(o0);
        o.y = ((unsigned)f2bf(o3) << 16) | f2bf(o2);
        *(uint2*)&h1u[node * 32 + 2 * l] = o;
    }
}

// fused mu+ls aggregation: one wave per node; wave-uniform 4-phase loop; float2 src logits
__global__ __launch_bounds__(256) void agg2(const unsigned* __restrict__ hml,
                                            const float* __restrict__ a2, const float2* __restrict__ a2s,
                                            const int* __restrict__ offs, const int* __restrict__ srcs,
                                            const float* __restrict__ bmu, const float* __restrict__ bls,
                                            float* __restrict__ out, int n) {
    int wid = threadIdx.x >> 6, lane = threadIdx.x & 63;
    int node = blockIdx.x * 4 + wid;
    if (node >= n) return;
    int q = lane >> 4, c = lane & 15;
    float admu = a2[node * 4 + 1], adls = a2[node * 4 + 3];
    float amu = 0.f, als = 0.f, dmu = 0.f, dls = 0.f;
    if (q == 0) {               // self loop
        float wmu = __expf(lrelu(a2[node * 4 + 0] + admu));
        float wls = __expf(lrelu(a2[node * 4 + 2] + adls));
        unsigned hv = hml[node * 16 + c];
        amu = wmu * bf_lo(hv); als = wls * bf_hi(hv);
        dmu = wmu; dls = wls;
    }
    int kb = offs[node];
    int deg = offs[node + 1] - kb;
    int pre = (lane < deg) ? srcs[kb + lane] : 0;
    for (int idx0 = 0; idx0 < deg; idx0 += 4) {
        int idx = idx0 + q;
        int idc = min(idx, deg - 1);
        int s = (idc < 64) ? __shfl(pre, idc, 64) : srcs[kb + idc];
        float2 ap = a2s[s];
        bool ok = idx < deg;
        float w1v = ok ? __expf(lrelu(ap.x + admu)) : 0.f;
        float w2v = ok ? __expf(lrelu(ap.y + adls)) : 0.f;
        unsigned hv = hml[s * 16 + c];
        dmu += w1v; dls += w2v;
        amu += w1v * bf_lo(hv);
        als += w2v * bf_hi(hv);
    }
    amu += __shfl_xor(amu, 16, 64); amu += __shfl_xor(amu, 32, 64);
    als += __shfl_xor(als, 16, 64); als += __shfl_xor(als, 32, 64);
    dmu += __shfl_xor(dmu, 16, 64); dmu += __shfl_xor(dmu, 32, 64);
    dls += __shfl_xor(dls, 16, 64); dls += __shfl_xor(dls, 32, 64);
    if (q == 0) {
        out[node * 16 + c] = amu / dmu + bmu[c];
        out[(size_t)n * 16 + node * 16 + c] = als / dls + bls[c];
    }
}

extern "C" void kernel_launch(void* const* d_in, const int* in_sizes, int n_in,
                              void* d_out, int out_size, void* d_ws, size_t ws_size,
                              hipStream_t stream) {
    const float* x    = (const float*)d_in[0];
    const int*   ei   = (const int*)d_in[1];
    const float* W1   = (const float*)d_in[2];
    const float* as1  = (const float*)d_in[3];
    const float* ad1  = (const float*)d_in[4];
    const float* b1   = (const float*)d_in[5];
    const float* Wmu  = (const float*)d_in[6];
    const float* asmu = (const float*)d_in[7];
    const float* admu = (const float*)d_in[8];
    const float* bmu  = (const float*)d_in[9];
    const float* Wls  = (const float*)d_in[10];
    const float* asls = (const float*)d_in[11];
    const float* adls = (const float*)d_in[12];
    const float* bls  = (const float*)d_in[13];
    float* out = (float*)d_out;

    int n = in_sizes[0] / 128;
    int E = in_sizes[1] / 2;
    int np = (n + 7) / 8;       // nodes per XCD partition

    char* ws = (char*)d_ws;
    size_t off = 0;
    auto alloc = [&](size_t b) { size_t p = off; off = (off + b + 255) & ~(size_t)255; return p; };

    unsigned short* hbf  = (unsigned short*)(ws + alloc((size_t)n * 64 * 2));
    unsigned*       h1u  = (unsigned*)(ws + alloc((size_t)n * 32 * 4));
    float*          a1   = (float*)(ws + alloc((size_t)n * 4 * 4));
    float2*         a1s  = (float2*)(ws + alloc((size_t)n * 8));
    unsigned*       hml  = (unsigned*)(ws + alloc((size_t)n * 16 * 4));
    float*          a2   = (float*)(ws + alloc((size_t)n * 4 * 4));
    float2*         a2s  = (float2*)(ws + alloc((size_t)n * 8));
    unsigned short* w1h  = (unsigned short*)(ws + alloc(80 * 128 * 2));
    unsigned short* w1l  = (unsigned short*)(ws + alloc(80 * 128 * 2));
    unsigned short* w2h  = (unsigned short*)(ws + alloc(48 * 64 * 2));
    unsigned short* w2l  = (unsigned short*)(ws + alloc(48 * 64 * 2));
    int*   deg    = (int*)(ws + alloc((size_t)n * 4));
    int*   offs   = (int*)(ws + alloc((size_t)(n + 1) * 4));
    int*   cursor = (int*)(ws + alloc((size_t)n * 4));
    int*   srcs   = (int*)(ws + alloc((size_t)E * 4));
    int*   bsums  = (int*)(ws + alloc(1024 * 4));

    int nb = (n + 255) / 256;

    hipMemsetAsync(deg, 0, (size_t)n * 4, stream);
    build_w<<<(128 * 80 + 64 * 48 + 255) / 256, 256, 0, stream>>>(W1, as1, ad1, Wmu, Wls, asmu, admu,
                                                                  asls, adls, w1h, w1l, w2h, w2l);
    gemm1<<<(n + 63) / 64, 256, 0, stream>>>(x, w1h, w1l, hbf, a1, a1s, n);
    count_deg_part<<<2048, 256, 0, stream>>>(ei + E, E, np, deg);
    block_sums<<<nb, 256, 0, stream>>>(deg, n, bsums);
    write_offs<<<nb, 256, 0, stream>>>(deg, bsums, nb, n, offs, cursor);
    scatter_part<<<2048, 256, 0, stream>>>(ei, ei + E, E, np, cursor, srcs);
    agg1<<<(n + 3) / 4, 256, 0, stream>>>((const unsigned*)hbf, a1, a1s, offs, srcs, b1, h1u, n);
    gemm2<<<(n + 63) / 64, 256, 0, stream>>>((const unsigned short*)h1u, w2h, w2l, hml, a2, a2s, n);
    agg2<<<(n + 3) / 4, 256, 0, stream>>>(hml, a2, a2s, offs, srcs, bmu, bls, out, n);
}